// Round 14
// baseline (1279.511 us; speedup 1.0000x reference)
//
#include <hip/hip_runtime.h>

#define HH 56
#define WW 56
#define CC 512
#define BB 32
#define LL (HH*WW)
#define MM (BB*LL)     // 100352 tokens
#define HID 2048

typedef __attribute__((ext_vector_type(8))) __bf16 bf16x8;
typedef __attribute__((ext_vector_type(4))) float f32x4;
typedef __attribute__((ext_vector_type(4))) short s16x4;

__device__ __forceinline__ short f2bf(float f) {
    union { float f; unsigned u; } c; c.f = f;
    unsigned r = c.u + 0x7fffu + ((c.u >> 16) & 1u);   // round-to-nearest-even
    return (short)(r >> 16);
}
__device__ __forceinline__ float bf2f(short s) {
    union { unsigned u; float f; } c; c.u = ((unsigned)(unsigned short)s) << 16;
    return c.f;
}

// fast gelu: v * t/(t+1), t = e^{2*0.7978845608*(v+0.044715 v^3)}
__device__ __forceinline__ float gelu_fast(float v) {
    float xg = 0.7978845608f * (v + 0.044715f * v * v * v);
    xg = fminf(xg, 15.0f);
    float t = __expf(2.0f * xg);
    return v * (t / (t + 1.0f));
}

// ---------------- f32 -> bf16 weight conversion ----------------
__global__ __launch_bounds__(256) void cvt_bf16(const float* __restrict__ in,
                                                short* __restrict__ out, int n) {
    int i = blockIdx.x * 256 + threadIdx.x;
    if (i < n) out[i] = f2bf(in[i]);
}

// -------- LayerNorm over 512 channels, 2 rows / block, float4 loads ---------
__global__ __launch_bounds__(256) void ln512v(const float* __restrict__ x,
                                              const float* __restrict__ g,
                                              const float* __restrict__ b,
                                              short* __restrict__ out) {
    const int t = threadIdx.x;
    const int rsel = t >> 7;                       // 0..1 row within block
    const int col = t & 127;                       // float4 column
    const long row = (long)blockIdx.x * 2 + rsel;
    const f32x4 v = ((const f32x4*)(x + row * 512))[col];
    float s = v[0] + v[1] + v[2] + v[3];
    float q = v[0]*v[0] + v[1]*v[1] + v[2]*v[2] + v[3]*v[3];
#pragma unroll
    for (int off = 32; off > 0; off >>= 1) {
        s += __shfl_xor(s, off, 64);
        q += __shfl_xor(q, off, 64);
    }
    __shared__ float red[8];
    const int wv = t >> 6;                         // 0..3 (waves 0,1=row0; 2,3=row1)
    if ((t & 63) == 0) { red[wv] = s; red[4 + wv] = q; }
    __syncthreads();
    s = red[rsel * 2] + red[rsel * 2 + 1];
    q = red[4 + rsel * 2] + red[4 + rsel * 2 + 1];
    const float mu = s * (1.0f / 512.0f);
    const float rs = rsqrtf(q * (1.0f / 512.0f) - mu * mu + 1e-5f);
    const f32x4 gv = ((const f32x4*)g)[col];
    const f32x4 bv = ((const f32x4*)b)[col];
    s16x4 o;
#pragma unroll
    for (int r = 0; r < 4; ++r)
        o[r] = f2bf((v[r] - mu) * rs * gv[r] + bv[r]);
    *(s16x4*)(out + row * 512 + col * 4) = o;
}

// ------- spatial (window) MLP + residual, 2 channels / thread ---------------
__global__ __launch_bounds__(256) void spatial_mlp(const short* __restrict__ xn,
                                                   const float* __restrict__ x,
                                                   const float* __restrict__ sw,
                                                   const float* __restrict__ sb,
                                                   float* x1) {
    const int head = blockIdx.y;
    const int t = threadIdx.x;
    const int chp = t & 15;                       // channel pair 0..15
    const int wloc = t >> 4;                      // 0..15 windows
    const int win = blockIdx.x * 16 + wloc;       // 0..2591
    const int b = win / 81;
    const int rr = win - b * 81;
    const int wi = rr / 9;
    const int wj = rr - wi * 9;
    const int c = head * 32 + chp * 2;

    float2 xv[49];
#pragma unroll
    for (int j = 0; j < 49; j++) {
        const int pr = wi * 7 + j / 7 - 4;        // padded row - P_T
        const int pc = wj * 7 + j % 7 - 4;        // padded col - P_L
        float2 v = {0.0f, 0.0f};
        if (pr >= 0 && pr < 56 && pc >= 0 && pc < 56) {
            const long idx = ((long)((b * 56 + pr) * 56 + pc)) * 512 + c;
            const ushort2 u = *(const ushort2*)(xn + idx);
            v.x = bf2f((short)u.x);
            v.y = bf2f((short)u.y);
        }
        xv[j] = v;
    }

    const float* swh = sw + head * 2401;
    const float* sbh = sb + head * 49;

#pragma unroll 1
    for (int t7 = 0; t7 < 7; t7++) {
        float2 acc[7];
#pragma unroll
        for (int ii = 0; ii < 7; ii++) {
            const float bb = sbh[t7 * 7 + ii];
            acc[ii].x = bb; acc[ii].y = bb;
        }
#pragma unroll
        for (int ii = 0; ii < 7; ii++) {
            const float* swr = swh + (t7 * 7 + ii) * 49;
#pragma unroll
            for (int j = 0; j < 49; j++) {
                acc[ii].x = fmaf(swr[j], xv[j].x, acc[ii].x);
                acc[ii].y = fmaf(swr[j], xv[j].y, acc[ii].y);
            }
        }
        const int pr = wi * 7 + t7 - 4;
        if (pr >= 0 && pr < 56) {
#pragma unroll
            for (int ii = 0; ii < 7; ii++) {
                const int pc = wj * 7 + ii - 4;
                if (pc >= 0 && pc < 56) {
                    const long idx = ((long)((b * 56 + pr) * 56 + pc)) * 512 + c;
                    const float2 rv = *(const float2*)(x + idx);
                    float2 o; o.x = rv.x + acc[ii].x; o.y = rv.y + acc[ii].y;
                    *(float2*)(x1 + idx) = o;
                }
            }
        }
    }
}

// ------- 128x128 4-wave bf16 GEMM, DEPTH-4 register-banked pipeline ----------
// The one untested lever: prefetch depth in REGISTERS (no LDS cost, so the
// depth x co-residency cancellation of rounds 5-13 doesn't apply).
// 4 named VGPR banks (rule #20: static names, loop unrolled x4, literal ids):
//   tile t: load bank[(t+3)&3] <- global tile t+3     (3-wall lead)
//           ds_write bank[(t+1)&3] -> slot[(t+1)&1]   (auto COUNTED vmcnt,
//                                     waits only loads issued 2 walls ago)
//           ds_read slot[t&1] frags (compiler counted lgkm; no blunt bracket,
//                                    no setprio - m190)
//           16 MFMA; lgkmcnt(0); s_barrier.
// LDS 2 slots = 32 KB -> 3 blocks/CU. Swizzle on ds_write addr (r13-verified).
template <int K, int N, bool GELU>
__global__ __launch_bounds__(256, 3) void gemmd4(const short* __restrict__ A,
                                                 const short* __restrict__ Bw,
                                                 const float* __restrict__ bias,
                                                 const float* res,
                                                 void* Cout) {
    __shared__ __attribute__((aligned(16))) char S[32768];  // A slots @0,8K; B @16K,24K
    const int tid = threadIdx.x;
    const int lane = tid & 63;
    const int wid = tid >> 6;
    const int wr = wid >> 1;          // 0..1  M-half (64 rows)
    const int wc = wid & 1;           // 0..1  N-half (64 cols)
    const int lr = lane & 15;
    const int kg = (lane >> 4) & 3;

    // T1: bijective XCD-aware remap (nwg % 8 == 0)
    const int gx = gridDim.x;
    const int lin = blockIdx.y * gx + blockIdx.x;
    const int cpx = (gx * gridDim.y) >> 3;
    const int orig = (lin & 7) * cpx + (lin >> 3);
    const long mBase = (long)(orig / gx) * 128;
    const long nBase = (long)(orig % gx) * 128;

    // global sources: LINEAR (swizzle on ds_write address)
    const int sRow = tid >> 2;                        // 0..63
    const short* aSrc0 = A + (mBase + sRow) * K + (tid & 3) * 8;
    const short* aSrc1 = A + (mBase + 64 + sRow) * K + (tid & 3) * 8;
    const short* bSrc0 = Bw + (nBase + sRow) * K + (tid & 3) * 8;
    const short* bSrc1 = Bw + (nBase + 64 + sRow) * K + (tid & 3) * 8;

    // ds_write byte offset: row*64 + (chunk ^ key(row))*16, key = (row>>1)&3
    const int wByte = sRow * 64 + (((tid & 3) ^ ((tid >> 3) & 3)) << 4);

    // read-side fragment offsets (verified 0-conflict)
    const int swzc = kg ^ ((lr >> 1) & 3);
    const int aOff = (wr * 64 + lr) * 64 + swzc * 16;    // + m*1024, m=0..3
    const int bOff = (wc * 64 + lr) * 64 + swzc * 16;    // + n*1024, n=0..3

    f32x4 acc[4][4] = {};
    const int NT = K / 32;
    static_assert((K / 32) % 4 == 0, "NT multiple of 4");

    // 4-deep named register banks
    f32x4 rA00, rA01, rB00, rB01;
    f32x4 rA10, rA11, rB10, rB11;
    f32x4 rA20, rA21, rB20, rB21;
    f32x4 rA30, rA31, rB30, rB31;

#define LOADBANK(B, T) do {                                                     \
        const long k0_ = (long)(T) * 32;                                        \
        rA##B##0 = *(const f32x4*)(aSrc0 + k0_);                                \
        rA##B##1 = *(const f32x4*)(aSrc1 + k0_);                                \
        rB##B##0 = *(const f32x4*)(bSrc0 + k0_);                                \
        rB##B##1 = *(const f32x4*)(bSrc1 + k0_);                                \
    } while (0)

#define WRITEBANK(B, SL) do {                                                   \
        *(f32x4*)(S + (SL) * 8192 + wByte)                = rA##B##0;           \
        *(f32x4*)(S + (SL) * 8192 + 4096 + wByte)         = rA##B##1;           \
        *(f32x4*)(S + 16384 + (SL) * 8192 + wByte)        = rB##B##0;           \
        *(f32x4*)(S + 16384 + (SL) * 8192 + 4096 + wByte) = rB##B##1;           \
    } while (0)

    // BODY(T runtime, SLOT/LB/WB literals): read slot SLOT (tile T),
    // write bank WB (tile T+1) -> slot 1-SLOT, load bank LB <- tile T+3.
#define BODY(T, SLOT, LB, WB) do {                                              \
        if ((T) + 3 < NT) LOADBANK(LB, (T) + 3);                                \
        if ((T) + 1 < NT) WRITEBANK(WB, 1 - (SLOT));                            \
        const char* Ab_ = S + (SLOT) * 8192;                                    \
        const char* Bb_ = S + 16384 + (SLOT) * 8192;                            \
        bf16x8 af[4], bfv[4];                                                   \
        _Pragma("unroll")                                                       \
        for (int m = 0; m < 4; ++m) af[m] = *(const bf16x8*)(Ab_ + aOff + m * 1024); \
        _Pragma("unroll")                                                       \
        for (int n = 0; n < 4; ++n) bfv[n] = *(const bf16x8*)(Bb_ + bOff + n * 1024); \
        _Pragma("unroll")                                                       \
        for (int m = 0; m < 4; ++m)                                             \
            _Pragma("unroll")                                                   \
            for (int n = 0; n < 4; ++n)                                         \
                acc[m][n] = __builtin_amdgcn_mfma_f32_16x16x32_bf16(bfv[n], af[m], acc[m][n], 0, 0, 0); \
        asm volatile("s_waitcnt lgkmcnt(0)" ::: "memory");                      \
        __builtin_amdgcn_s_barrier();                                           \
    } while (0)

    // prologue: banks 0,1,2 <- tiles 0,1,2; bank0 -> slot0
    LOADBANK(0, 0);
    LOADBANK(1, 1);
    LOADBANK(2, 2);
    WRITEBANK(0, 0);                  // auto counted vmcnt (waits bank0 only)
    asm volatile("s_waitcnt lgkmcnt(0)" ::: "memory");
    __builtin_amdgcn_s_barrier();

    for (int t4 = 0; t4 < NT; t4 += 4) {
        BODY(t4 + 0, 0, 3, 1);
        BODY(t4 + 1, 1, 0, 2);
        BODY(t4 + 2, 0, 1, 3);
        BODY(t4 + 3, 1, 2, 0);
    }
#undef BODY
#undef WRITEBANK
#undef LOADBANK

    // epilogue: operand-swapped fragment = C^T layout:
    //   C row  = mBase + wr*64 + m*16 + lr
    //   C cols = nBase + wc*64 + n*16 + kg*4 + (0..3)   (consecutive)
#pragma unroll
    for (int n = 0; n < 4; ++n) {
        const long col0 = nBase + wc * 64 + n * 16 + kg * 4;
        const f32x4 bv4 = *(const f32x4*)(bias + col0);
#pragma unroll
        for (int m = 0; m < 4; ++m) {
            const long row = mBase + wr * 64 + m * 16 + lr;
            const long idx = row * N + col0;
            if (GELU) {
                s16x4 o;
#pragma unroll
                for (int r = 0; r < 4; ++r)
                    o[r] = f2bf(gelu_fast(acc[m][n][r] + bv4[r]));
                *(s16x4*)((short*)Cout + idx) = o;
            } else {
                const f32x4 rv = *(const f32x4*)(res + idx);
                f32x4 o;
#pragma unroll
                for (int r = 0; r < 4; ++r) o[r] = acc[m][n][r] + bv4[r] + rv[r];
                *(f32x4*)((float*)Cout + idx) = o;
            }
        }
    }
}

extern "C" void kernel_launch(void* const* d_in, const int* in_sizes, int n_in,
                              void* d_out, int out_size, void* d_ws, size_t ws_size,
                              hipStream_t stream) {
    const float* x    = (const float*)d_in[0];
    const float* n1g  = (const float*)d_in[1];
    const float* n1b  = (const float*)d_in[2];
    const float* sw   = (const float*)d_in[3];
    const float* sb   = (const float*)d_in[4];
    const float* n2g  = (const float*)d_in[5];
    const float* n2b  = (const float*)d_in[6];
    const float* fc1w = (const float*)d_in[7];
    const float* fc1b = (const float*)d_in[8];
    const float* fc2w = (const float*)d_in[9];
    const float* fc2b = (const float*)d_in[10];
    float* out = (float*)d_out;

    // workspace layout (bytes)
    char* ws = (char*)d_ws;
    short* xn  = (short*)ws;                      // MM*512*2    = 102,760,448  (xn, then xn2)
    short* hb  = (short*)(ws + 102760448);        // MM*2048*2   = 411,041,792
    short* w1b = (short*)(ws + 513802240);        // 2048*512*2  =   2,097,152
    short* w2b = (short*)(ws + 515899392);        // 512*2048*2  =   2,097,152

    cvt_bf16<<<4096, 256, 0, stream>>>(fc1w, w1b, 2048 * 512);
    cvt_bf16<<<4096, 256, 0, stream>>>(fc2w, w2b, 512 * 2048);

    // LN1: x -> xn (bf16), 2 rows/block float4
    ln512v<<<MM / 2, 256, 0, stream>>>(x, n1g, n1b, xn);

    // spatial MLP + residual: x1 = x + y  (into d_out), 2ch/thread
    spatial_mlp<<<dim3(162, 16), 256, 0, stream>>>(xn, x, sw, sb, out);

    // LN2: x1 -> xn2 (bf16, reuse xn buffer)
    ln512v<<<MM / 2, 256, 0, stream>>>(out, n2g, n2b, xn);

    // FC1 + gelu -> h (bf16)   grid: 16 N-tiles x 784 M-tiles
    gemmd4<512, 2048, true><<<dim3(16, 784), 256, 0, stream>>>(xn, w1b, fc1b, nullptr, hb);

    // FC2 + bias + residual -> out (f32, reads x1 from d_out in place)
    gemmd4<2048, 512, false><<<dim3(4, 784), 256, 0, stream>>>(hb, w2b, fc2b, out, out);
}

// Round 15
// 1077.478 us; speedup vs baseline: 1.1875x; 1.1875x over previous
//
#include <hip/hip_runtime.h>

#define HH 56
#define WW 56
#define CC 512
#define BB 32
#define LL (HH*WW)
#define MM (BB*LL)     // 100352 tokens
#define HID 2048

typedef __attribute__((ext_vector_type(8))) __bf16 bf16x8;
typedef __attribute__((ext_vector_type(4))) float f32x4;
typedef __attribute__((ext_vector_type(4))) short s16x4;

__device__ __forceinline__ short f2bf(float f) {
    union { float f; unsigned u; } c; c.f = f;
    unsigned r = c.u + 0x7fffu + ((c.u >> 16) & 1u);   // round-to-nearest-even
    return (short)(r >> 16);
}
__device__ __forceinline__ float bf2f(short s) {
    union { unsigned u; float f; } c; c.u = ((unsigned)(unsigned short)s) << 16;
    return c.f;
}

// fast gelu, constant-folded (9 VALU): v * e/(e+1), e = exp(v*(1.5958+0.08943*v^2))
__device__ __forceinline__ float gelu_fast(float v) {
    const float t0 = v * v;
    const float p = fmaf(t0, 0.08943f, 1.59577f);      // 2*0.79788*(1 + 0.044715 v^2)
    float xg = fminf(v * p, 30.0f);                    // avoid inf/inf
    const float e = __expf(xg);
    return v * (e * __frcp_rn(e + 1.0f));
}

// ---------------- f32 -> bf16 weight conversion ----------------
__global__ __launch_bounds__(256) void cvt_bf16(const float* __restrict__ in,
                                                short* __restrict__ out, int n) {
    int i = blockIdx.x * 256 + threadIdx.x;
    if (i < n) out[i] = f2bf(in[i]);
}

// -------- LayerNorm over 512 channels, 2 rows / block, float4 loads ---------
__global__ __launch_bounds__(256) void ln512v(const float* __restrict__ x,
                                              const float* __restrict__ g,
                                              const float* __restrict__ b,
                                              short* __restrict__ out) {
    const int t = threadIdx.x;
    const int rsel = t >> 7;                       // 0..1 row within block
    const int col = t & 127;                       // float4 column
    const long row = (long)blockIdx.x * 2 + rsel;
    const f32x4 v = ((const f32x4*)(x + row * 512))[col];
    float s = v[0] + v[1] + v[2] + v[3];
    float q = v[0]*v[0] + v[1]*v[1] + v[2]*v[2] + v[3]*v[3];
#pragma unroll
    for (int off = 32; off > 0; off >>= 1) {
        s += __shfl_xor(s, off, 64);
        q += __shfl_xor(q, off, 64);
    }
    __shared__ float red[8];
    const int wv = t >> 6;                         // 0..3 (waves 0,1=row0; 2,3=row1)
    if ((t & 63) == 0) { red[wv] = s; red[4 + wv] = q; }
    __syncthreads();
    s = red[rsel * 2] + red[rsel * 2 + 1];
    q = red[4 + rsel * 2] + red[4 + rsel * 2 + 1];
    const float mu = s * (1.0f / 512.0f);
    const float rs = rsqrtf(q * (1.0f / 512.0f) - mu * mu + 1e-5f);
    const f32x4 gv = ((const f32x4*)g)[col];
    const f32x4 bv = ((const f32x4*)b)[col];
    s16x4 o;
#pragma unroll
    for (int r = 0; r < 4; ++r)
        o[r] = f2bf((v[r] - mu) * rs * gv[r] + bv[r]);
    *(s16x4*)(out + row * 512 + col * 4) = o;
}

// ------- spatial (window) MLP + residual, 2 channels / thread ---------------
__global__ __launch_bounds__(256) void spatial_mlp(const short* __restrict__ xn,
                                                   const float* __restrict__ x,
                                                   const float* __restrict__ sw,
                                                   const float* __restrict__ sb,
                                                   float* x1) {
    const int head = blockIdx.y;
    const int t = threadIdx.x;
    const int chp = t & 15;                       // channel pair 0..15
    const int wloc = t >> 4;                      // 0..15 windows
    const int win = blockIdx.x * 16 + wloc;       // 0..2591
    const int b = win / 81;
    const int rr = win - b * 81;
    const int wi = rr / 9;
    const int wj = rr - wi * 9;
    const int c = head * 32 + chp * 2;

    float2 xv[49];
#pragma unroll
    for (int j = 0; j < 49; j++) {
        const int pr = wi * 7 + j / 7 - 4;        // padded row - P_T
        const int pc = wj * 7 + j % 7 - 4;        // padded col - P_L
        float2 v = {0.0f, 0.0f};
        if (pr >= 0 && pr < 56 && pc >= 0 && pc < 56) {
            const long idx = ((long)((b * 56 + pr) * 56 + pc)) * 512 + c;
            const ushort2 u = *(const ushort2*)(xn + idx);
            v.x = bf2f((short)u.x);
            v.y = bf2f((short)u.y);
        }
        xv[j] = v;
    }

    const float* swh = sw + head * 2401;
    const float* sbh = sb + head * 49;

#pragma unroll 1
    for (int t7 = 0; t7 < 7; t7++) {
        float2 acc[7];
#pragma unroll
        for (int ii = 0; ii < 7; ii++) {
            const float bb = sbh[t7 * 7 + ii];
            acc[ii].x = bb; acc[ii].y = bb;
        }
#pragma unroll
        for (int ii = 0; ii < 7; ii++) {
            const float* swr = swh + (t7 * 7 + ii) * 49;
#pragma unroll
            for (int j = 0; j < 49; j++) {
                acc[ii].x = fmaf(swr[j], xv[j].x, acc[ii].x);
                acc[ii].y = fmaf(swr[j], xv[j].y, acc[ii].y);
            }
        }
        const int pr = wi * 7 + t7 - 4;
        if (pr >= 0 && pr < 56) {
#pragma unroll
            for (int ii = 0; ii < 7; ii++) {
                const int pc = wj * 7 + ii - 4;
                if (pc >= 0 && pc < 56) {
                    const long idx = ((long)((b * 56 + pr) * 56 + pc)) * 512 + c;
                    const float2 rv = *(const float2*)(x + idx);
                    float2 o; o.x = rv.x + acc[ii].x; o.y = rv.y + acc[ii].y;
                    *(float2*)(x1 + idx) = o;
                }
            }
        }
    }
}

// ------- 256x128 4-wave bf16 GEMM, per-wave 128x64, ring-3, 2 blocks/CU ------
// r8 structure with the SWIZZLE BUG FIXED: r8's XOR key row&3 left rows
// {0,4,8,12} on one bank-start (4-way conflict, SQ_LDS_BANK_CONFLICT=1.93e7,
// m136: 1.58x LDS cost). Correct key for 64B rows is (row>>1)&3 (r5-verified,
// 0 conflicts): bank-start = row*16 + chunk*4 covers all 8 starts, 2-way=free.
// Structural wins vs r5: 1.5x FLOP per LDS-read (12 b128 per 32 MFMA) and
// half the barrier-walls per FLOP (392 vs 784 walls/CU).
template <int K, int N, bool GELU>
__global__ __launch_bounds__(256, 2) void gemm2x(const short* __restrict__ A,
                                                 const short* __restrict__ Bw,
                                                 const float* __restrict__ bias,
                                                 const float* res,
                                                 void* Cout) {
    __shared__ __attribute__((aligned(16))) short S[36864];  // 72 KB
    const int tid = threadIdx.x;
    const int lane = tid & 63;
    const int wid = tid >> 6;
    const int wr = wid >> 1;           // 0..1  M-half (128 rows)
    const int wc = wid & 1;            // 0..1  N-half (64 cols)
    const int lr = lane & 15;
    const int kg = (lane >> 4) & 3;

    // T1: bijective XCD-aware remap (nwg % 8 == 0)
    const int gx = gridDim.x;
    const int lin = blockIdx.y * gx + blockIdx.x;
    const int cpx = (gx * gridDim.y) >> 3;
    const int orig = (lin & 7) * cpx + (lin >> 3);
    const long mBase = (long)(orig / gx) * 256;
    const long nBase = (long)(orig % gx) * 128;

    // staging source (pre-swizzled column chunk; LDS dest linear)
    // row = tid>>2 (0..63), chunk key = (row>>1)&3 = (tid>>3)&3   [FIXED]
    const int sRow = tid >> 2;
    const int sChunk = (tid & 3) ^ ((tid >> 3) & 3);
    const short* aS = A + (mBase + sRow) * K + sChunk * 8;
    const short* bS = Bw + (nBase + sRow) * K + sChunk * 8;

    // ring slot r: A at r*16384, B at 49152 + r*8192
    auto stage = [&](int rbuf, int t) {
        const long k0 = (long)t * 32;
        char* Ad = (char*)S + rbuf * 16384 + tid * 16;
        char* Bd = (char*)S + 49152 + rbuf * 8192 + tid * 16;
#pragma unroll
        for (int j = 0; j < 4; ++j)       // A: 256 rows x 32 k
            __builtin_amdgcn_global_load_lds(
                (const __attribute__((address_space(1))) void*)(aS + k0 + (long)j * 64 * K),
                (__attribute__((address_space(3))) void*)(Ad + j * 4096), 16, 0, 0);
#pragma unroll
        for (int j = 0; j < 2; ++j)       // B: 128 rows x 32 k
            __builtin_amdgcn_global_load_lds(
                (const __attribute__((address_space(1))) void*)(bS + k0 + (long)j * 64 * K),
                (__attribute__((address_space(3))) void*)(Bd + j * 4096), 16, 0, 0);
    };

    // fragment LDS byte offsets: row*64 + (kg^((row>>1)&3))*16, row&7 -> lr&7 [FIXED]
    const int swz = (kg ^ ((lr >> 1) & 3)) * 16;
    const int aOff = (wr * 128 + lr) * 64 + swz;      // + m*1024, m=0..7
    const int bOff = (wc * 64 + lr) * 64 + swz;       // + n*1024, n=0..3

    f32x4 acc[8][4] = {};

    stage(0, 0); stage(1, 1);                         // 12 loads in flight
    asm volatile("s_waitcnt vmcnt(6)" ::: "memory");  // tile 0 landed
    __builtin_amdgcn_s_barrier();

    const int NT = K / 32;
    int cb = 0;
    for (int t = 0; t < NT; ++t) {
        if (t + 2 < NT) {
            const int sb = cb >= 1 ? cb - 1 : 2;      // (cb+2)%3
            stage(sb, t + 2);
        }
        const char* Ab = (const char*)S + cb * 16384;
        const char* Bb = (const char*)S + 49152 + cb * 8192;
        bf16x8 af[8], bfv[4];
#pragma unroll
        for (int m = 0; m < 8; ++m) af[m] = *(const bf16x8*)(Ab + aOff + m * 1024);
#pragma unroll
        for (int n = 0; n < 4; ++n) bfv[n] = *(const bf16x8*)(Bb + bOff + n * 1024);
        asm volatile("s_waitcnt lgkmcnt(0)" ::: "memory");
        __builtin_amdgcn_s_setprio(1);
#pragma unroll
        for (int m = 0; m < 8; ++m)
#pragma unroll
            for (int n = 0; n < 4; ++n)
                acc[m][n] = __builtin_amdgcn_mfma_f32_16x16x32_bf16(bfv[n], af[m],
                                                                    acc[m][n], 0, 0, 0);
        __builtin_amdgcn_s_setprio(0);
        // boundary: tile t+1's 6 loads landed (t+2's 6 stay in flight)
        if (t + 2 < NT)      asm volatile("s_waitcnt vmcnt(6)" ::: "memory");
        else if (t + 1 < NT) asm volatile("s_waitcnt vmcnt(0)" ::: "memory");
        __builtin_amdgcn_s_barrier();
        cb = cb + 1 == 3 ? 0 : cb + 1;
    }

    // epilogue: operand-swapped fragment = C^T layout:
    //   C row  = mBase + wr*128 + m*16 + lr
    //   C cols = nBase + wc*64 + n*16 + kg*4 + (0..3)   (consecutive)
#pragma unroll
    for (int n = 0; n < 4; ++n) {
        const long col0 = nBase + wc * 64 + n * 16 + kg * 4;
        const f32x4 bv4 = *(const f32x4*)(bias + col0);
#pragma unroll
        for (int m = 0; m < 8; ++m) {
            const long row = mBase + wr * 128 + m * 16 + lr;
            const long idx = row * N + col0;
            if (GELU) {
                s16x4 o;
#pragma unroll
                for (int r = 0; r < 4; ++r)
                    o[r] = f2bf(gelu_fast(acc[m][n][r] + bv4[r]));
                *(s16x4*)((short*)Cout + idx) = o;
            } else {
                const f32x4 rv = *(const f32x4*)(res + idx);
                f32x4 o;
#pragma unroll
                for (int r = 0; r < 4; ++r) o[r] = acc[m][n][r] + bv4[r] + rv[r];
                *(f32x4*)((float*)Cout + idx) = o;
            }
        }
    }
}

extern "C" void kernel_launch(void* const* d_in, const int* in_sizes, int n_in,
                              void* d_out, int out_size, void* d_ws, size_t ws_size,
                              hipStream_t stream) {
    const float* x    = (const float*)d_in[0];
    const float* n1g  = (const float*)d_in[1];
    const float* n1b  = (const float*)d_in[2];
    const float* sw   = (const float*)d_in[3];
    const float* sb   = (const float*)d_in[4];
    const float* n2g  = (const float*)d_in[5];
    const float* n2b  = (const float*)d_in[6];
    const float* fc1w = (const float*)d_in[7];
    const float* fc1b = (const float*)d_in[8];
    const float* fc2w = (const float*)d_in[9];
    const float* fc2b = (const float*)d_in[10];
    float* out = (float*)d_out;

    // workspace layout (bytes)
    char* ws = (char*)d_ws;
    short* xn  = (short*)ws;                      // MM*512*2    = 102,760,448  (xn, then xn2)
    short* hb  = (short*)(ws + 102760448);        // MM*2048*2   = 411,041,792
    short* w1b = (short*)(ws + 513802240);        // 2048*512*2  =   2,097,152
    short* w2b = (short*)(ws + 515899392);        // 512*2048*2  =   2,097,152

    cvt_bf16<<<4096, 256, 0, stream>>>(fc1w, w1b, 2048 * 512);
    cvt_bf16<<<4096, 256, 0, stream>>>(fc2w, w2b, 512 * 2048);

    // LN1: x -> xn (bf16), 2 rows/block float4
    ln512v<<<MM / 2, 256, 0, stream>>>(x, n1g, n1b, xn);

    // spatial MLP + residual: x1 = x + y  (into d_out), 2ch/thread
    spatial_mlp<<<dim3(162, 16), 256, 0, stream>>>(xn, x, sw, sb, out);

    // LN2: x1 -> xn2 (bf16, reuse xn buffer)
    ln512v<<<MM / 2, 256, 0, stream>>>(out, n2g, n2b, xn);

    // FC1 + gelu -> h (bf16)   grid: 16 N-tiles x 392 M-tiles
    gemm2x<512, 2048, true><<<dim3(16, 392), 256, 0, stream>>>(xn, w1b, fc1b, nullptr, hb);

    // FC2 + bias + residual -> out (f32, reads x1 from d_out in place)
    gemm2x<2048, 512, false><<<dim3(4, 392), 256, 0, stream>>>(hb, w2b, fc2b, out, out);
}

// Round 16
// 1064.859 us; speedup vs baseline: 1.2016x; 1.0119x over previous
//
#include <hip/hip_runtime.h>

#define HH 56
#define WW 56
#define CC 512
#define BB 32
#define LL (HH*WW)
#define MM (BB*LL)     // 100352 tokens
#define HID 2048

typedef __attribute__((ext_vector_type(8))) __bf16 bf16x8;
typedef __attribute__((ext_vector_type(4))) float f32x4;
typedef __attribute__((ext_vector_type(4))) short s16x4;

__device__ __forceinline__ short f2bf(float f) {
    union { float f; unsigned u; } c; c.f = f;
    unsigned r = c.u + 0x7fffu + ((c.u >> 16) & 1u);   // round-to-nearest-even
    return (short)(r >> 16);
}
__device__ __forceinline__ float bf2f(short s) {
    union { unsigned u; float f; } c; c.u = ((unsigned)(unsigned short)s) << 16;
    return c.f;
}

// fast gelu: v * t/(t+1), t = e^{2*0.7978845608*(v+0.044715 v^3)}  (r12 version)
__device__ __forceinline__ float gelu_fast(float v) {
    float xg = 0.7978845608f * (v + 0.044715f * v * v * v);
    xg = fminf(xg, 15.0f);
    float t = __expf(2.0f * xg);
    return v * (t / (t + 1.0f));
}

// ---------------- f32 -> bf16 weight conversion ----------------
__global__ __launch_bounds__(256) void cvt_bf16(const float* __restrict__ in,
                                                short* __restrict__ out, int n) {
    int i = blockIdx.x * 256 + threadIdx.x;
    if (i < n) out[i] = f2bf(in[i]);
}

// -------- LayerNorm over 512 channels, 2 rows / block, float4 loads ---------
__global__ __launch_bounds__(256) void ln512v(const float* __restrict__ x,
                                              const float* __restrict__ g,
                                              const float* __restrict__ b,
                                              short* __restrict__ out) {
    const int t = threadIdx.x;
    const int rsel = t >> 7;                       // 0..1 row within block
    const int col = t & 127;                       // float4 column
    const long row = (long)blockIdx.x * 2 + rsel;
    const f32x4 v = ((const f32x4*)(x + row * 512))[col];
    float s = v[0] + v[1] + v[2] + v[3];
    float q = v[0]*v[0] + v[1]*v[1] + v[2]*v[2] + v[3]*v[3];
#pragma unroll
    for (int off = 32; off > 0; off >>= 1) {
        s += __shfl_xor(s, off, 64);
        q += __shfl_xor(q, off, 64);
    }
    __shared__ float red[8];
    const int wv = t >> 6;                         // 0..3 (waves 0,1=row0; 2,3=row1)
    if ((t & 63) == 0) { red[wv] = s; red[4 + wv] = q; }
    __syncthreads();
    s = red[rsel * 2] + red[rsel * 2 + 1];
    q = red[4 + rsel * 2] + red[4 + rsel * 2 + 1];
    const float mu = s * (1.0f / 512.0f);
    const float rs = rsqrtf(q * (1.0f / 512.0f) - mu * mu + 1e-5f);
    const f32x4 gv = ((const f32x4*)g)[col];
    const f32x4 bv = ((const f32x4*)b)[col];
    s16x4 o;
#pragma unroll
    for (int r = 0; r < 4; ++r)
        o[r] = f2bf((v[r] - mu) * rs * gv[r] + bv[r]);
    *(s16x4*)(out + row * 512 + col * 4) = o;
}

// ------- spatial (window) MLP + residual, 2 channels / thread ---------------
__global__ __launch_bounds__(256) void spatial_mlp(const short* __restrict__ xn,
                                                   const float* __restrict__ x,
                                                   const float* __restrict__ sw,
                                                   const float* __restrict__ sb,
                                                   float* x1) {
    const int head = blockIdx.y;
    const int t = threadIdx.x;
    const int chp = t & 15;                       // channel pair 0..15
    const int wloc = t >> 4;                      // 0..15 windows
    const int win = blockIdx.x * 16 + wloc;       // 0..2591
    const int b = win / 81;
    const int rr = win - b * 81;
    const int wi = rr / 9;
    const int wj = rr - wi * 9;
    const int c = head * 32 + chp * 2;

    float2 xv[49];
#pragma unroll
    for (int j = 0; j < 49; j++) {
        const int pr = wi * 7 + j / 7 - 4;        // padded row - P_T
        const int pc = wj * 7 + j % 7 - 4;        // padded col - P_L
        float2 v = {0.0f, 0.0f};
        if (pr >= 0 && pr < 56 && pc >= 0 && pc < 56) {
            const long idx = ((long)((b * 56 + pr) * 56 + pc)) * 512 + c;
            const ushort2 u = *(const ushort2*)(xn + idx);
            v.x = bf2f((short)u.x);
            v.y = bf2f((short)u.y);
        }
        xv[j] = v;
    }

    const float* swh = sw + head * 2401;
    const float* sbh = sb + head * 49;

#pragma unroll 1
    for (int t7 = 0; t7 < 7; t7++) {
        float2 acc[7];
#pragma unroll
        for (int ii = 0; ii < 7; ii++) {
            const float bb = sbh[t7 * 7 + ii];
            acc[ii].x = bb; acc[ii].y = bb;
        }
#pragma unroll
        for (int ii = 0; ii < 7; ii++) {
            const float* swr = swh + (t7 * 7 + ii) * 49;
#pragma unroll
            for (int j = 0; j < 49; j++) {
                acc[ii].x = fmaf(swr[j], xv[j].x, acc[ii].x);
                acc[ii].y = fmaf(swr[j], xv[j].y, acc[ii].y);
            }
        }
        const int pr = wi * 7 + t7 - 4;
        if (pr >= 0 && pr < 56) {
#pragma unroll
            for (int ii = 0; ii < 7; ii++) {
                const int pc = wj * 7 + ii - 4;
                if (pc >= 0 && pc < 56) {
                    const long idx = ((long)((b * 56 + pr) * 56 + pc)) * 512 + c;
                    const float2 rv = *(const float2*)(x + idx);
                    float2 o; o.x = rv.x + acc[ii].x; o.y = rv.y + acc[ii].y;
                    *(float2*)(x1 + idx) = o;
                }
            }
        }
    }
}

// ---------------- 128x128 4-wave bf16 GEMM, ring-3 counted-vmcnt -------------
// SESSION-BEST structure (r5/r12, 418 us/GEMM). A[M,K] rm, Bw[N,K] rm (B^T).
// BK=32, ring-3 48 KB -> 3 blocks/CU. Per K-tile: stage(t+2) [4 gload_lds];
// 8x ds_read_b128; lgkmcnt(0); setprio(1); 16 MFMA; setprio(0);
// counted vmcnt(4); ONE s_barrier. T1 XCD remap; verified 0-conflict XOR
// swizzle (key=(row>>1)&3); operand-swapped MFMA -> vectorized epilogue.
template <int K, int N, bool GELU>
__global__ __launch_bounds__(256, 3) void gemm128(const short* __restrict__ A,
                                                  const short* __restrict__ Bw,
                                                  const float* __restrict__ bias,
                                                  const float* res,
                                                  void* Cout) {
    __shared__ __attribute__((aligned(16))) short S[24576];  // 48 KB
    const int tid = threadIdx.x;
    const int lane = tid & 63;
    const int wid = tid >> 6;
    const int wr = wid >> 1;          // 0..1  M-half (64 rows)
    const int wc = wid & 1;           // 0..1  N-half (64 cols)
    const int lr = lane & 15;
    const int kg = (lane >> 4) & 3;

    // T1: bijective XCD-aware remap (nwg % 8 == 0)
    const int gx = gridDim.x;
    const int lin = blockIdx.y * gx + blockIdx.x;
    const int cpx = (gx * gridDim.y) >> 3;
    const int orig = (lin & 7) * cpx + (lin >> 3);
    const long mBase = (long)(orig / gx) * 128;
    const long nBase = (long)(orig % gx) * 128;

    // staging source (per-thread, fixed): pre-swizzled K-chunk.
    const int sRow = tid >> 2;                        // 0..63
    const int sChunk = (tid & 3) ^ ((tid >> 3) & 3);  // key = (row>>1)&3
    const short* aSrc0 = A + (mBase + sRow) * K + sChunk * 8;
    const short* aSrc1 = A + (mBase + 64 + sRow) * K + sChunk * 8;
    const short* bSrc0 = Bw + (nBase + sRow) * K + sChunk * 8;
    const short* bSrc1 = Bw + (nBase + 64 + sRow) * K + sChunk * 8;

    auto stage = [&](int buf, int t) {
        const long k0 = (long)t * 32;
        char* Ad = (char*)S + buf * 8192 + tid * 16;
        char* Bd = (char*)S + 24576 + buf * 8192 + tid * 16;
        __builtin_amdgcn_global_load_lds(
            (const __attribute__((address_space(1))) void*)(aSrc0 + k0),
            (__attribute__((address_space(3))) void*)Ad, 16, 0, 0);
        __builtin_amdgcn_global_load_lds(
            (const __attribute__((address_space(1))) void*)(aSrc1 + k0),
            (__attribute__((address_space(3))) void*)(Ad + 4096), 16, 0, 0);
        __builtin_amdgcn_global_load_lds(
            (const __attribute__((address_space(1))) void*)(bSrc0 + k0),
            (__attribute__((address_space(3))) void*)Bd, 16, 0, 0);
        __builtin_amdgcn_global_load_lds(
            (const __attribute__((address_space(1))) void*)(bSrc1 + k0),
            (__attribute__((address_space(3))) void*)(Bd + 4096), 16, 0, 0);
    };

    // fragment LDS byte offsets: row*64 + swizzled-chunk*16, key=(row>>1)&3
    const int swzc = kg ^ ((lr >> 1) & 3);
    const int aOff = (wr * 64 + lr) * 64 + swzc * 16;    // + m*1024, m=0..3
    const int bOff = (wc * 64 + lr) * 64 + swzc * 16;    // + n*1024, n=0..3

    f32x4 acc[4][4] = {};

    stage(0, 0); stage(1, 1);
    asm volatile("s_waitcnt vmcnt(4)" ::: "memory");     // tile 0 landed
    __builtin_amdgcn_s_barrier();

    const int NT = K / 32;
    int cb = 0;                                          // current ring slot
    for (int t = 0; t < NT; ++t) {
        if (t + 2 < NT) {
            const int sb = cb >= 1 ? cb - 1 : 2;         // (cb+2)%3
            stage(sb, t + 2);
        }
        const char* Ab = (const char*)S + cb * 8192;
        const char* Bb = (const char*)S + 24576 + cb * 8192;
        bf16x8 af[4], bf[4];
#pragma unroll
        for (int m = 0; m < 4; ++m) af[m] = *(const bf16x8*)(Ab + aOff + m * 1024);
#pragma unroll
        for (int n = 0; n < 4; ++n) bf[n] = *(const bf16x8*)(Bb + bOff + n * 1024);
        asm volatile("s_waitcnt lgkmcnt(0)" ::: "memory");
        __builtin_amdgcn_s_setprio(1);
#pragma unroll
        for (int m = 0; m < 4; ++m)
#pragma unroll
            for (int n = 0; n < 4; ++n)
                acc[m][n] = __builtin_amdgcn_mfma_f32_16x16x32_bf16(bf[n], af[m],
                                                                    acc[m][n], 0, 0, 0);
        __builtin_amdgcn_s_setprio(0);
        // boundary: buf[t+1] must be landed before next tile reads it
        if (t + 1 < NT) {
            if (t + 2 < NT) asm volatile("s_waitcnt vmcnt(4)" ::: "memory");
            else            asm volatile("s_waitcnt vmcnt(0)" ::: "memory");
        }
        __builtin_amdgcn_s_barrier();
        cb = cb + 1 == 3 ? 0 : cb + 1;
    }

    // epilogue: operand-swapped fragment = C^T layout:
    //   C row  = mBase + wr*64 + m*16 + lr
    //   C cols = nBase + wc*64 + n*16 + kg*4 + (0..3)   (consecutive)
#pragma unroll
    for (int n = 0; n < 4; ++n) {
        const long col0 = nBase + wc * 64 + n * 16 + kg * 4;
        const f32x4 bv4 = *(const f32x4*)(bias + col0);
#pragma unroll
        for (int m = 0; m < 4; ++m) {
            const long row = mBase + wr * 64 + m * 16 + lr;
            const long idx = row * N + col0;
            if (GELU) {
                s16x4 o;
#pragma unroll
                for (int r = 0; r < 4; ++r)
                    o[r] = f2bf(gelu_fast(acc[m][n][r] + bv4[r]));
                *(s16x4*)((short*)Cout + idx) = o;
            } else {
                const f32x4 rv = *(const f32x4*)(res + idx);
                f32x4 o;
#pragma unroll
                for (int r = 0; r < 4; ++r) o[r] = acc[m][n][r] + bv4[r] + rv[r];
                *(f32x4*)((float*)Cout + idx) = o;
            }
        }
    }
}

extern "C" void kernel_launch(void* const* d_in, const int* in_sizes, int n_in,
                              void* d_out, int out_size, void* d_ws, size_t ws_size,
                              hipStream_t stream) {
    const float* x    = (const float*)d_in[0];
    const float* n1g  = (const float*)d_in[1];
    const float* n1b  = (const float*)d_in[2];
    const float* sw   = (const float*)d_in[3];
    const float* sb   = (const float*)d_in[4];
    const float* n2g  = (const float*)d_in[5];
    const float* n2b  = (const float*)d_in[6];
    const float* fc1w = (const float*)d_in[7];
    const float* fc1b = (const float*)d_in[8];
    const float* fc2w = (const float*)d_in[9];
    const float* fc2b = (const float*)d_in[10];
    float* out = (float*)d_out;

    // workspace layout (bytes)
    char* ws = (char*)d_ws;
    short* xn  = (short*)ws;                      // MM*512*2    = 102,760,448  (xn, then xn2)
    short* hb  = (short*)(ws + 102760448);        // MM*2048*2   = 411,041,792
    short* w1b = (short*)(ws + 513802240);        // 2048*512*2  =   2,097,152
    short* w2b = (short*)(ws + 515899392);        // 512*2048*2  =   2,097,152

    cvt_bf16<<<4096, 256, 0, stream>>>(fc1w, w1b, 2048 * 512);
    cvt_bf16<<<4096, 256, 0, stream>>>(fc2w, w2b, 512 * 2048);

    // LN1: x -> xn (bf16), 2 rows/block float4
    ln512v<<<MM / 2, 256, 0, stream>>>(x, n1g, n1b, xn);

    // spatial MLP + residual: x1 = x + y  (into d_out), 2ch/thread
    spatial_mlp<<<dim3(162, 16), 256, 0, stream>>>(xn, x, sw, sb, out);

    // LN2: x1 -> xn2 (bf16, reuse xn buffer)
    ln512v<<<MM / 2, 256, 0, stream>>>(out, n2g, n2b, xn);

    // FC1 + gelu -> h (bf16)   grid: 16 N-tiles x 784 M-tiles
    gemm128<512, 2048, true><<<dim3(16, 784), 256, 0, stream>>>(xn, w1b, fc1b, nullptr, hb);

    // FC2 + bias + residual -> out (f32, reads x1 from d_out in place)
    gemm128<2048, 512, false><<<dim3(4, 784), 256, 0, stream>>>(hb, w2b, fc2b, out, out);
}

// Round 17
// 976.331 us; speedup vs baseline: 1.3105x; 1.0907x over previous
//
#include <hip/hip_runtime.h>

#define HH 56
#define WW 56
#define CC 512
#define BB 32
#define LL (HH*WW)
#define MM (BB*LL)     // 100352 tokens
#define HID 2048

typedef __attribute__((ext_vector_type(8))) __bf16 bf16x8;
typedef __attribute__((ext_vector_type(4))) float f32x4;
typedef __attribute__((ext_vector_type(4))) short s16x4;

__device__ __forceinline__ short f2bf(float f) {
    union { float f; unsigned u; } c; c.f = f;
    unsigned r = c.u + 0x7fffu + ((c.u >> 16) & 1u);   // round-to-nearest-even
    return (short)(r >> 16);
}
__device__ __forceinline__ float bf2f(short s) {
    union { unsigned u; float f; } c; c.u = ((unsigned)(unsigned short)s) << 16;
    return c.f;
}

// fast gelu: v * t/(t+1), t = e^{2*0.7978845608*(v+0.044715 v^3)}  (r12 version)
__device__ __forceinline__ float gelu_fast(float v) {
    float xg = 0.7978845608f * (v + 0.044715f * v * v * v);
    xg = fminf(xg, 15.0f);
    float t = __expf(2.0f * xg);
    return v * (t / (t + 1.0f));
}

// ---------------- f32 -> bf16 weight conversion (both weights, one launch) --
__global__ __launch_bounds__(256) void cvt2_bf16(const float* __restrict__ in1,
                                                 short* __restrict__ out1,
                                                 const float* __restrict__ in2,
                                                 short* __restrict__ out2, int n) {
    int i = blockIdx.x * 256 + threadIdx.x;
    if (i < n) out1[i] = f2bf(in1[i]);
    else if (i < 2 * n) out2[i - n] = f2bf(in2[i - n]);
}

// -------- LayerNorm over 512 channels, 2 rows / block, float4 loads ---------
__global__ __launch_bounds__(256) void ln512v(const float* __restrict__ x,
                                              const float* __restrict__ g,
                                              const float* __restrict__ b,
                                              short* __restrict__ out) {
    const int t = threadIdx.x;
    const int rsel = t >> 7;                       // 0..1 row within block
    const int col = t & 127;                       // float4 column
    const long row = (long)blockIdx.x * 2 + rsel;
    const f32x4 v = ((const f32x4*)(x + row * 512))[col];
    float s = v[0] + v[1] + v[2] + v[3];
    float q = v[0]*v[0] + v[1]*v[1] + v[2]*v[2] + v[3]*v[3];
#pragma unroll
    for (int off = 32; off > 0; off >>= 1) {
        s += __shfl_xor(s, off, 64);
        q += __shfl_xor(q, off, 64);
    }
    __shared__ float red[8];
    const int wv = t >> 6;                         // 0..3 (waves 0,1=row0; 2,3=row1)
    if ((t & 63) == 0) { red[wv] = s; red[4 + wv] = q; }
    __syncthreads();
    s = red[rsel * 2] + red[rsel * 2 + 1];
    q = red[4 + rsel * 2] + red[4 + rsel * 2 + 1];
    const float mu = s * (1.0f / 512.0f);
    const float rs = rsqrtf(q * (1.0f / 512.0f) - mu * mu + 1e-5f);
    const f32x4 gv = ((const f32x4*)g)[col];
    const f32x4 bv = ((const f32x4*)b)[col];
    s16x4 o;
#pragma unroll
    for (int r = 0; r < 4; ++r)
        o[r] = f2bf((v[r] - mu) * rs * gv[r] + bv[r]);
    *(s16x4*)(out + row * 512 + col * 4) = o;
}

// ------- spatial MLP, INTERIOR windows (wi,wj in 1..7): branch-free ---------
// 60% of windows need no bounds checks at all (pr in [3,51], pc in [3,51]).
__global__ __launch_bounds__(256) void spatial_int(const short* __restrict__ xn,
                                                   const float* __restrict__ x,
                                                   const float* __restrict__ sw,
                                                   const float* __restrict__ sb,
                                                   float* x1) {
    const int head = blockIdx.y;
    const int t = threadIdx.x;
    const int chp = t & 15;                       // channel pair 0..15
    const int wloc = t >> 4;                      // 0..15 windows
    const int wlin = blockIdx.x * 16 + wloc;      // 0..1567 (32 batches x 49)
    const int b = wlin / 49;
    const int r = wlin - b * 49;
    const int wi = 1 + r / 7;
    const int wj = 1 + r - (r / 7) * 7;
    const int c = head * 32 + chp * 2;
    const long base = ((long)((b * 56 + wi * 7 - 4) * 56) + (wj * 7 - 4)) * 512 + c;

    float2 xv[49];
#pragma unroll
    for (int j = 0; j < 49; j++) {
        const long idx = base + (long)(j / 7) * (56 * 512) + (j % 7) * 512;
        const ushort2 u = *(const ushort2*)(xn + idx);
        xv[j].x = bf2f((short)u.x);
        xv[j].y = bf2f((short)u.y);
    }

    const float* swh = sw + head * 2401;
    const float* sbh = sb + head * 49;

#pragma unroll 1
    for (int t7 = 0; t7 < 7; t7++) {
        float2 acc[7];
#pragma unroll
        for (int ii = 0; ii < 7; ii++) {
            const float bb = sbh[t7 * 7 + ii];
            acc[ii].x = bb; acc[ii].y = bb;
        }
#pragma unroll
        for (int ii = 0; ii < 7; ii++) {
            const float* swr = swh + (t7 * 7 + ii) * 49;
#pragma unroll
            for (int j = 0; j < 49; j++) {
                acc[ii].x = fmaf(swr[j], xv[j].x, acc[ii].x);
                acc[ii].y = fmaf(swr[j], xv[j].y, acc[ii].y);
            }
        }
        const long rowbase = base + (long)t7 * (56 * 512);
#pragma unroll
        for (int ii = 0; ii < 7; ii++) {
            const long idx = rowbase + ii * 512;
            const float2 rv = *(const float2*)(x + idx);
            float2 o; o.x = rv.x + acc[ii].x; o.y = rv.y + acc[ii].y;
            *(float2*)(x1 + idx) = o;
        }
    }
}

// ------- spatial MLP, BOUNDARY windows (ring of 9x9 minus 7x7 = 32/batch) ---
__global__ __launch_bounds__(256) void spatial_bnd(const short* __restrict__ xn,
                                                   const float* __restrict__ x,
                                                   const float* __restrict__ sw,
                                                   const float* __restrict__ sb,
                                                   float* x1) {
    const int head = blockIdx.y;
    const int t = threadIdx.x;
    const int chp = t & 15;                       // channel pair 0..15
    const int wloc = t >> 4;                      // 0..15 windows
    const int wlin = blockIdx.x * 16 + wloc;      // 0..1023 (32 batches x 32)
    const int b = wlin >> 5;
    const int r = wlin & 31;
    int wi, wj;
    if (r < 9)       { wi = 0;      wj = r;      }
    else if (r < 18) { wi = 8;      wj = r - 9;  }
    else if (r < 25) { wi = r - 17; wj = 0;      }   // wi 1..7
    else             { wi = r - 24; wj = 8;      }   // wi 1..7
    const int c = head * 32 + chp * 2;

    float2 xv[49];
#pragma unroll
    for (int j = 0; j < 49; j++) {
        const int pr = wi * 7 + j / 7 - 4;        // padded row - P_T
        const int pc = wj * 7 + j % 7 - 4;        // padded col - P_L
        float2 v = {0.0f, 0.0f};
        if (pr >= 0 && pr < 56 && pc >= 0 && pc < 56) {
            const long idx = ((long)((b * 56 + pr) * 56 + pc)) * 512 + c;
            const ushort2 u = *(const ushort2*)(xn + idx);
            v.x = bf2f((short)u.x);
            v.y = bf2f((short)u.y);
        }
        xv[j] = v;
    }

    const float* swh = sw + head * 2401;
    const float* sbh = sb + head * 49;

#pragma unroll 1
    for (int t7 = 0; t7 < 7; t7++) {
        float2 acc[7];
#pragma unroll
        for (int ii = 0; ii < 7; ii++) {
            const float bb = sbh[t7 * 7 + ii];
            acc[ii].x = bb; acc[ii].y = bb;
        }
#pragma unroll
        for (int ii = 0; ii < 7; ii++) {
            const float* swr = swh + (t7 * 7 + ii) * 49;
#pragma unroll
            for (int j = 0; j < 49; j++) {
                acc[ii].x = fmaf(swr[j], xv[j].x, acc[ii].x);
                acc[ii].y = fmaf(swr[j], xv[j].y, acc[ii].y);
            }
        }
        const int pr = wi * 7 + t7 - 4;
        if (pr >= 0 && pr < 56) {
#pragma unroll
            for (int ii = 0; ii < 7; ii++) {
                const int pc = wj * 7 + ii - 4;
                if (pc >= 0 && pc < 56) {
                    const long idx = ((long)((b * 56 + pr) * 56 + pc)) * 512 + c;
                    const float2 rv = *(const float2*)(x + idx);
                    float2 o; o.x = rv.x + acc[ii].x; o.y = rv.y + acc[ii].y;
                    *(float2*)(x1 + idx) = o;
                }
            }
        }
    }
}

// ---------------- 128x128 4-wave bf16 GEMM, ring-3 counted-vmcnt -------------
// SESSION-BEST structure (r5/r12/r16, ~418 us/GEMM). Epilogue store order
// swapped to m-outer/n-inner: one row's 4 stores (128B contiguous for bf16)
// are now temporally adjacent -> TCC write-combine (FC1 WRITE_SIZE was 1.6x
// ideal with n-outer order).
template <int K, int N, bool GELU>
__global__ __launch_bounds__(256, 3) void gemm128(const short* __restrict__ A,
                                                  const short* __restrict__ Bw,
                                                  const float* __restrict__ bias,
                                                  const float* res,
                                                  void* Cout) {
    __shared__ __attribute__((aligned(16))) short S[24576];  // 48 KB
    const int tid = threadIdx.x;
    const int lane = tid & 63;
    const int wid = tid >> 6;
    const int wr = wid >> 1;          // 0..1  M-half (64 rows)
    const int wc = wid & 1;           // 0..1  N-half (64 cols)
    const int lr = lane & 15;
    const int kg = (lane >> 4) & 3;

    // T1: bijective XCD-aware remap (nwg % 8 == 0)
    const int gx = gridDim.x;
    const int lin = blockIdx.y * gx + blockIdx.x;
    const int cpx = (gx * gridDim.y) >> 3;
    const int orig = (lin & 7) * cpx + (lin >> 3);
    const long mBase = (long)(orig / gx) * 128;
    const long nBase = (long)(orig % gx) * 128;

    // staging source (per-thread, fixed): pre-swizzled K-chunk.
    const int sRow = tid >> 2;                        // 0..63
    const int sChunk = (tid & 3) ^ ((tid >> 3) & 3);  // key = (row>>1)&3
    const short* aSrc0 = A + (mBase + sRow) * K + sChunk * 8;
    const short* aSrc1 = A + (mBase + 64 + sRow) * K + sChunk * 8;
    const short* bSrc0 = Bw + (nBase + sRow) * K + sChunk * 8;
    const short* bSrc1 = Bw + (nBase + 64 + sRow) * K + sChunk * 8;

    auto stage = [&](int buf, int t) {
        const long k0 = (long)t * 32;
        char* Ad = (char*)S + buf * 8192 + tid * 16;
        char* Bd = (char*)S + 24576 + buf * 8192 + tid * 16;
        __builtin_amdgcn_global_load_lds(
            (const __attribute__((address_space(1))) void*)(aSrc0 + k0),
            (__attribute__((address_space(3))) void*)Ad, 16, 0, 0);
        __builtin_amdgcn_global_load_lds(
            (const __attribute__((address_space(1))) void*)(aSrc1 + k0),
            (__attribute__((address_space(3))) void*)(Ad + 4096), 16, 0, 0);
        __builtin_amdgcn_global_load_lds(
            (const __attribute__((address_space(1))) void*)(bSrc0 + k0),
            (__attribute__((address_space(3))) void*)Bd, 16, 0, 0);
        __builtin_amdgcn_global_load_lds(
            (const __attribute__((address_space(1))) void*)(bSrc1 + k0),
            (__attribute__((address_space(3))) void*)(Bd + 4096), 16, 0, 0);
    };

    // fragment LDS byte offsets: row*64 + swizzled-chunk*16, key=(row>>1)&3
    const int swzc = kg ^ ((lr >> 1) & 3);
    const int aOff = (wr * 64 + lr) * 64 + swzc * 16;    // + m*1024, m=0..3
    const int bOff = (wc * 64 + lr) * 64 + swzc * 16;    // + n*1024, n=0..3

    f32x4 acc[4][4] = {};

    stage(0, 0); stage(1, 1);
    asm volatile("s_waitcnt vmcnt(4)" ::: "memory");     // tile 0 landed
    __builtin_amdgcn_s_barrier();

    const int NT = K / 32;
    int cb = 0;                                          // current ring slot
    for (int t = 0; t < NT; ++t) {
        if (t + 2 < NT) {
            const int sb = cb >= 1 ? cb - 1 : 2;         // (cb+2)%3
            stage(sb, t + 2);
        }
        const char* Ab = (const char*)S + cb * 8192;
        const char* Bb = (const char*)S + 24576 + cb * 8192;
        bf16x8 af[4], bf[4];
#pragma unroll
        for (int m = 0; m < 4; ++m) af[m] = *(const bf16x8*)(Ab + aOff + m * 1024);
#pragma unroll
        for (int n = 0; n < 4; ++n) bf[n] = *(const bf16x8*)(Bb + bOff + n * 1024);
        asm volatile("s_waitcnt lgkmcnt(0)" ::: "memory");
        __builtin_amdgcn_s_setprio(1);
#pragma unroll
        for (int m = 0; m < 4; ++m)
#pragma unroll
            for (int n = 0; n < 4; ++n)
                acc[m][n] = __builtin_amdgcn_mfma_f32_16x16x32_bf16(bf[n], af[m],
                                                                    acc[m][n], 0, 0, 0);
        __builtin_amdgcn_s_setprio(0);
        // boundary: buf[t+1] must be landed before next tile reads it
        if (t + 1 < NT) {
            if (t + 2 < NT) asm volatile("s_waitcnt vmcnt(4)" ::: "memory");
            else            asm volatile("s_waitcnt vmcnt(0)" ::: "memory");
        }
        __builtin_amdgcn_s_barrier();
        cb = cb + 1 == 3 ? 0 : cb + 1;
    }

    // epilogue (m-outer, n-inner): operand-swapped fragment = C^T layout:
    //   C row  = mBase + wr*64 + m*16 + lr
    //   C cols = nBase + wc*64 + n*16 + kg*4 + (0..3)   (consecutive)
    f32x4 bv4[4];
#pragma unroll
    for (int n = 0; n < 4; ++n)
        bv4[n] = *(const f32x4*)(bias + nBase + wc * 64 + n * 16 + kg * 4);
#pragma unroll
    for (int m = 0; m < 4; ++m) {
        const long row = mBase + wr * 64 + m * 16 + lr;
        const long rowbase = row * N + nBase + wc * 64 + kg * 4;
#pragma unroll
        for (int n = 0; n < 4; ++n) {
            const long idx = rowbase + n * 16;
            if (GELU) {
                s16x4 o;
#pragma unroll
                for (int r = 0; r < 4; ++r)
                    o[r] = f2bf(gelu_fast(acc[m][n][r] + bv4[n][r]));
                *(s16x4*)((short*)Cout + idx) = o;
            } else {
                const f32x4 rv = *(const f32x4*)(res + idx);
                f32x4 o;
#pragma unroll
                for (int r = 0; r < 4; ++r) o[r] = acc[m][n][r] + bv4[n][r] + rv[r];
                *(f32x4*)((float*)Cout + idx) = o;
            }
        }
    }
}

extern "C" void kernel_launch(void* const* d_in, const int* in_sizes, int n_in,
                              void* d_out, int out_size, void* d_ws, size_t ws_size,
                              hipStream_t stream) {
    const float* x    = (const float*)d_in[0];
    const float* n1g  = (const float*)d_in[1];
    const float* n1b  = (const float*)d_in[2];
    const float* sw   = (const float*)d_in[3];
    const float* sb   = (const float*)d_in[4];
    const float* n2g  = (const float*)d_in[5];
    const float* n2b  = (const float*)d_in[6];
    const float* fc1w = (const float*)d_in[7];
    const float* fc1b = (const float*)d_in[8];
    const float* fc2w = (const float*)d_in[9];
    const float* fc2b = (const float*)d_in[10];
    float* out = (float*)d_out;

    // workspace layout (bytes)
    char* ws = (char*)d_ws;
    short* xn  = (short*)ws;                      // MM*512*2    = 102,760,448  (xn, then xn2)
    short* hb  = (short*)(ws + 102760448);        // MM*2048*2   = 411,041,792
    short* w1b = (short*)(ws + 513802240);        // 2048*512*2  =   2,097,152
    short* w2b = (short*)(ws + 515899392);        // 512*2048*2  =   2,097,152

    cvt2_bf16<<<8192, 256, 0, stream>>>(fc1w, w1b, fc2w, w2b, 2048 * 512);

    // LN1: x -> xn (bf16), 2 rows/block float4
    ln512v<<<MM / 2, 256, 0, stream>>>(x, n1g, n1b, xn);

    // spatial MLP + residual: x1 = x + y (into d_out); interior/boundary split
    spatial_int<<<dim3(98, 16), 256, 0, stream>>>(xn, x, sw, sb, out);   // 32x49 windows
    spatial_bnd<<<dim3(64, 16), 256, 0, stream>>>(xn, x, sw, sb, out);   // 32x32 windows

    // LN2: x1 -> xn2 (bf16, reuse xn buffer)
    ln512v<<<MM / 2, 256, 0, stream>>>(out, n2g, n2b, xn);

    // FC1 + gelu -> h (bf16)   grid: 16 N-tiles x 784 M-tiles
    gemm128<512, 2048, true><<<dim3(16, 784), 256, 0, stream>>>(xn, w1b, fc1b, nullptr, hb);

    // FC2 + bias + residual -> out (f32, reads x1 from d_out in place)
    gemm128<2048, 512, false><<<dim3(4, 784), 256, 0, stream>>>(hb, w2b, fc2b, out, out);
}